// Round 3
// baseline (431.021 us; speedup 1.0000x reference)
//
#include <hip/hip_runtime.h>
#include <cstdint>
#include <cstddef>

// GAT layer, N=8192, F=128.  Round 6: fold k1b into kA; drop WhT; no-atomic M2.
// kA  : block-partitioned fused kernel.
//       bids 0..255    : Wh = h@W -> Bpack (MFMA B-frag order) + s12 (LDS
//                        transpose reduce from fp32 acc) + per-block max(s2)
//       bids 256..2303 : pack adj>0 into bitmap bm[rg][jw][m] (8 MiB),
//                        int4 loads (16B/lane) + nibble + shfl_xor OR-combine
//       wh blocks first so their compute hides under pack's 268MB BW stream.
// k1c : reduce 256 block-maxes -> M2; per-index exp factors (tau,kap1,kap2 per
//       row; E=exp(s2),F=exp(.2*s2) per col)
// k2  : 32x32x16 f16 MFMA, 1 wave = 32 rows x 128 f, j split into S chunks,
//       NO LDS / NO barriers; bitmap 2-deep prefetch, EF 1-deep,
//       B 1KB coalesced loads from L2, s_setprio(1) around MFMA cluster.
// k3  : combine S partials, ELU, store.
// R5 post-mortem: -22us matched prediction; ~320us of dur is harness 2x1GiB
// poison-fill floor. This round: -1 dispatch, -4MiB WhT traffic, s12 for free.

#define NROW 8192
#define FDIM 128

typedef _Float16 f16;
typedef f16 f16x8 __attribute__((ext_vector_type(8)));
typedef float f32x4 __attribute__((ext_vector_type(4)));
typedef float f32x16 __attribute__((ext_vector_type(16)));

// workspace byte offsets (WS_WHT slot retired, kept as padding)
#define WS_BP  (2u*1024u*1024u)              // f16 Bpack[512][4][64][8]  : 2 MiB
#define WS_S12 (4u*1024u*1024u)              // float2 s12[8192]          : 64 KiB
#define WS_RC  (WS_S12 + 64u*1024u)          // float4 RC[8192]           : 128 KiB
#define WS_EF  (WS_RC + 128u*1024u)          // float2 EF[8192]           : 64 KiB
#define WS_M2  (WS_EF + 64u*1024u)           // float M2v[256] (pad 4K)
#define WS_PWS (WS_M2 + 4u*1024u)            // float Pws[S][8192][128]   : S*4 MiB
// Dws = WS_PWS + S*4MiB : float Dws[S][8192]
// bm  = after Dws       : unsigned bm[256][256][32] : 8 MiB

// ---------------- kA: fused pack || (wh + s12) ----------------
__global__ __launch_bounds__(256) void kA_wh_pack(const float* __restrict__ h,
                                                  const float* __restrict__ W,
                                                  const float* __restrict__ a,
                                                  const int* __restrict__ adj,
                                                  f16* __restrict__ Bp,
                                                  unsigned* __restrict__ bm,
                                                  float2* __restrict__ s12,
                                                  float* __restrict__ M2v) {
  __shared__ float smem[4736];  // hT[128][36] -> WhS[32][132] + part[2][8][32]
  const int bid = (int)blockIdx.x;
  const int t = (int)threadIdx.x;

  if (bid >= 256) {
    // ---- pack part: bm[rg][jw][m] bit b = adj[rg*32+m][jw*32+b] ----
    const int pb = bid - 256;
    const int w = t >> 6, l = t & 63;
    const int r = pb * 4 + w;  // one row per wave
    const int rg = r >> 5, m = r & 31;
    const int* ap = adj + (size_t)r * NROW;
    unsigned* bp = bm + (size_t)rg * (256 * 32) + m;  // + jw*32
    const int g = l >> 3;  // 8-lane group -> one 32-col word
    for (int jb = 0; jb < NROW; jb += 256) {
      int4 v = *(const int4*)(ap + jb + 4 * l);  // lane covers cols 4l..4l+3
      unsigned nib = (v.x > 0 ? 1u : 0u) | (v.y > 0 ? 2u : 0u) |
                     (v.z > 0 ? 4u : 0u) | (v.w > 0 ? 8u : 0u);
      unsigned word = nib << (4 * (l & 7));
      word |= (unsigned)__shfl_xor((int)word, 1, 64);
      word |= (unsigned)__shfl_xor((int)word, 2, 64);
      word |= (unsigned)__shfl_xor((int)word, 4, 64);
      if ((l & 7) == 0) bp[(size_t)((jb >> 5) + g) * 32] = word;
    }
    return;
  }

  // ---- wh part: Wh = h @ W -> Bpack + s12 + block max(s2) ----
  const int rb = bid * 32;
  const f32x4* hv = (const f32x4*)(h + (size_t)rb * FDIM);
#pragma unroll
  for (int i = 0; i < 4; ++i) {
    int fidx = t + i * 256;
    f32x4 v = hv[fidx];
    int e0 = fidx * 4;
    int r = e0 >> 7, k = e0 & 127;
    smem[(k + 0) * 36 + r] = v[0];
    smem[(k + 1) * 36 + r] = v[1];
    smem[(k + 2) * 36 + r] = v[2];
    smem[(k + 3) * 36 + r] = v[3];
  }
  __syncthreads();
  const int f = t & 127, rh = t >> 7;
  f32x4 z = {0.f, 0.f, 0.f, 0.f};
  f32x4 acc0 = z, acc1 = z, acc2 = z, acc3 = z;
  for (int k = 0; k < 128; ++k) {
    float w = W[k * FDIM + f];
    const f32x4* hp = (const f32x4*)(smem + k * 36 + rh * 16);
    acc0 += hp[0] * w;
    acc1 += hp[1] * w;
    acc2 += hp[2] * w;
    acc3 += hp[3] * w;
  }
  union { f16 hx[16]; uint4 u[2]; } pk;
#pragma unroll
  for (int q = 0; q < 4; ++q) {
    pk.hx[0 + q]  = (f16)acc0[q];   // hx[i] = Wh[rb + rh*16 + i][f]
    pk.hx[4 + q]  = (f16)acc1[q];
    pk.hx[8 + q]  = (f16)acc2[q];
    pk.hx[12 + q] = (f16)acc3[q];
  }
  // Bpack[jt=j/16][nt=f/32][lane=(f&31)+32*kb][e] = Wh[jt*16+kb*8+e][f]
  f16* bdst = Bp + ((size_t)((bid * 2 + rh) * 4 + (f >> 5)) * 64 + (f & 31)) * 8;
  *(uint4*)bdst = pk.u[0];
  *(uint4*)(bdst + 256) = pk.u[1];   // +32 lanes * 8

  // s12: transpose fp32 acc into LDS WhS[32][132], then f-reduce
  __syncthreads();  // all hT reads done; reuse smem
#pragma unroll
  for (int q = 0; q < 4; ++q) {
    smem[(rh * 16 + 0  + q) * 132 + f] = acc0[q];
    smem[(rh * 16 + 4  + q) * 132 + f] = acc1[q];
    smem[(rh * 16 + 8  + q) * 132 + f] = acc2[q];
    smem[(rh * 16 + 12 + q) * 132 + f] = acc3[q];
  }
  __syncthreads();
  {
    const int row = t & 31, fc = t >> 5;  // 8 chunks of 16 f
    const float* wrow = smem + row * 132 + fc * 16;
    float s1 = 0.f, s2 = 0.f;
#pragma unroll
    for (int ff = 0; ff < 16; ++ff) {
      float wv = wrow[ff];
      int fg = fc * 16 + ff;
      s1 = fmaf(wv, a[fg], s1);
      s2 = fmaf(wv, a[128 + fg], s2);
    }
    float* part = smem + 4224;  // [2][8][32]
    __syncthreads();  // WhS reads done before overwrite (part overlaps? no, 4224>4223) - ordering with below writes anyway
    part[0 * 256 + fc * 32 + row] = s1;
    part[1 * 256 + fc * 32 + row] = s2;
    __syncthreads();
    if (t < 32) {
      float s1t = 0.f, s2t = 0.f;
#pragma unroll
      for (int c2 = 0; c2 < 8; ++c2) {
        s1t += part[c2 * 32 + t];
        s2t += part[256 + c2 * 32 + t];
      }
      s12[rb + t] = make_float2(s1t, s2t);
      float mx = s2t;
#pragma unroll
      for (int off = 16; off; off >>= 1) mx = fmaxf(mx, __shfl_xor(mx, off, 64));
      if (t == 0) M2v[bid] = mx;  // plain store, no atomics/init needed
    }
  }
}

// ---------------- k1c: reduce M2; per-index exp factors ----------------
__global__ __launch_bounds__(256) void k1c_prep(const float2* __restrict__ s12,
                                                const float* __restrict__ M2v,
                                                float4* __restrict__ RC,
                                                float2* __restrict__ EF) {
  __shared__ float red[4];
  const int t = (int)threadIdx.x;
  float v = M2v[t];  // 256 block maxes
#pragma unroll
  for (int off = 32; off; off >>= 1) v = fmaxf(v, __shfl_xor(v, off, 64));
  if ((t & 63) == 0) red[t >> 6] = v;
  __syncthreads();
  float M2 = fmaxf(fmaxf(red[0], red[1]), fmaxf(red[2], red[3]));
  int j = (int)blockIdx.x * 256 + t;
  float2 s = s12[j];
  float c = s.x + M2;
  c = fmaxf(c, 0.2f * c);  // upper bound on all row scores => p <= 1
  RC[j] = make_float4(__expf(-s.x), __expf(s.x - c), __expf(0.2f * s.x - c), 0.f);
  EF[j] = make_float2(__expf(s.y), __expf(0.2f * s.y));
}

// ---------------- k2: barrier-free fused masked-softmax @ Wh ----------------
// wave wid: rg = wid&255 (32-row group), c = wid>>8 (j chunk of jspan).
// lane: m = L&31 (row), kb = L>>5 (k-half). Per 32-j iter: 2 A-frags, 8 MFMA.
// bitmap word: one dword/lane/iter, 128 B/wave, 2-deep prefetch (cold-HBM).
__global__ __launch_bounds__(256) void k2_main(const unsigned* __restrict__ bm,
                                               const f16* __restrict__ Bp,
                                               const float4* __restrict__ RC,
                                               const float* __restrict__ EF,
                                               float* __restrict__ Pws,
                                               float* __restrict__ Dws,
                                               int jspan) {
  const int tid = (int)threadIdx.x;
  const int L = tid & 63, w = tid >> 6;
  const int wid = (int)blockIdx.x * 4 + w;
  const int rg = wid & 255;
  const int c = wid >> 8;
  const int rb = rg * 32;
  const int m = L & 31, kb = L >> 5;
  const int row = rb + m;
  const int j0 = c * jspan;
  const int niter = jspan >> 5;

  const float4 rc = RC[row];
  const float tau = rc.x, kap1 = rc.y, kap2 = rc.z;

  const unsigned* wbase = bm + ((size_t)rg * 256 + (size_t)(j0 >> 5)) * 32 + m;
  const f32x4* ep = (const f32x4*)(EF + 2 * (j0 + kb * 8));
  const f16* bp = Bp + (size_t)(j0 >> 4) * 2048 + L * 8;  // tile stride 2048 f16

  // prefetch: bitmap 2-deep (cold HBM ~900cyc), EF 1-deep (L2-hot)
  unsigned WD  = wbase[0];
  unsigned WDn = wbase[32];
  f32x4 E0 = ep[0], E1 = ep[1], E2 = ep[2], E3 = ep[3];
  f32x4 E4 = ep[8], E5 = ep[9], E6 = ep[10], E7 = ep[11];

  f32x16 zz = {0.f};
  f32x16 acc[4] = {zz, zz, zz, zz};
  float dloc = 0.f;

  for (int it = 0; it < niter; ++it) {
    // B loads first (L2 ~200cyc hides under the score build below)
    const f16* bt = bp + (size_t)it * 4096;
    f16x8 B00 = *(const f16x8*)(bt);
    f16x8 B01 = *(const f16x8*)(bt + 512);
    f16x8 B02 = *(const f16x8*)(bt + 1024);
    f16x8 B03 = *(const f16x8*)(bt + 1536);
    f16x8 B10 = *(const f16x8*)(bt + 2048);
    f16x8 B11 = *(const f16x8*)(bt + 2560);
    f16x8 B12 = *(const f16x8*)(bt + 3072);
    f16x8 B13 = *(const f16x8*)(bt + 3584);

    // score build: p = adjbit ? exp(leaky(s1+s2)-c) : 0, branch-factored, no exp
    // af0[e] <- bit kb*8+e ; af1[e] <- bit 16+kb*8+e of WD
    const unsigned u0 = WD >> (kb * 8);
    const unsigned u1 = u0 >> 16;
    f16x8 af0, af1;
    {
      float p;
      p = (E0[0] > tau) ? E0[0] * kap1 : E0[1] * kap2; p = (u0 & 1u)   ? p : 0.f; dloc += p; af0[0] = (f16)p;
      p = (E0[2] > tau) ? E0[2] * kap1 : E0[3] * kap2; p = (u0 & 2u)   ? p : 0.f; dloc += p; af0[1] = (f16)p;
      p = (E1[0] > tau) ? E1[0] * kap1 : E1[1] * kap2; p = (u0 & 4u)   ? p : 0.f; dloc += p; af0[2] = (f16)p;
      p = (E1[2] > tau) ? E1[2] * kap1 : E1[3] * kap2; p = (u0 & 8u)   ? p : 0.f; dloc += p; af0[3] = (f16)p;
      p = (E2[0] > tau) ? E2[0] * kap1 : E2[1] * kap2; p = (u0 & 16u)  ? p : 0.f; dloc += p; af0[4] = (f16)p;
      p = (E2[2] > tau) ? E2[2] * kap1 : E2[3] * kap2; p = (u0 & 32u)  ? p : 0.f; dloc += p; af0[5] = (f16)p;
      p = (E3[0] > tau) ? E3[0] * kap1 : E3[1] * kap2; p = (u0 & 64u)  ? p : 0.f; dloc += p; af0[6] = (f16)p;
      p = (E3[2] > tau) ? E3[2] * kap1 : E3[3] * kap2; p = (u0 & 128u) ? p : 0.f; dloc += p; af0[7] = (f16)p;
      p = (E4[0] > tau) ? E4[0] * kap1 : E4[1] * kap2; p = (u1 & 1u)   ? p : 0.f; dloc += p; af1[0] = (f16)p;
      p = (E4[2] > tau) ? E4[2] * kap1 : E4[3] * kap2; p = (u1 & 2u)   ? p : 0.f; dloc += p; af1[1] = (f16)p;
      p = (E5[0] > tau) ? E5[0] * kap1 : E5[1] * kap2; p = (u1 & 4u)   ? p : 0.f; dloc += p; af1[2] = (f16)p;
      p = (E5[2] > tau) ? E5[2] * kap1 : E5[3] * kap2; p = (u1 & 8u)   ? p : 0.f; dloc += p; af1[3] = (f16)p;
      p = (E6[0] > tau) ? E6[0] * kap1 : E6[1] * kap2; p = (u1 & 16u)  ? p : 0.f; dloc += p; af1[4] = (f16)p;
      p = (E6[2] > tau) ? E6[2] * kap1 : E6[3] * kap2; p = (u1 & 32u)  ? p : 0.f; dloc += p; af1[5] = (f16)p;
      p = (E7[0] > tau) ? E7[0] * kap1 : E7[1] * kap2; p = (u1 & 64u)  ? p : 0.f; dloc += p; af1[6] = (f16)p;
      p = (E7[2] > tau) ? E7[2] * kap1 : E7[3] * kap2; p = (u1 & 128u) ? p : 0.f; dloc += p; af1[7] = (f16)p;
    }

    // advance prefetch: bitmap 2-deep, EF 1-deep
    int nx = (it + 2 < niter) ? (it + 2) : (niter - 1);
    WD = WDn;
    WDn = wbase[(size_t)nx * 32];
    int adv = (it < niter - 1) ? 1 : 0;
    ep += adv * 16;
    E0 = ep[0]; E1 = ep[1]; E2 = ep[2]; E3 = ep[3];
    E4 = ep[8]; E5 = ep[9]; E6 = ep[10]; E7 = ep[11];

    __builtin_amdgcn_s_setprio(1);
    acc[0] = __builtin_amdgcn_mfma_f32_32x32x16_f16(af0, B00, acc[0], 0, 0, 0);
    acc[1] = __builtin_amdgcn_mfma_f32_32x32x16_f16(af0, B01, acc[1], 0, 0, 0);
    acc[2] = __builtin_amdgcn_mfma_f32_32x32x16_f16(af0, B02, acc[2], 0, 0, 0);
    acc[3] = __builtin_amdgcn_mfma_f32_32x32x16_f16(af0, B03, acc[3], 0, 0, 0);
    acc[0] = __builtin_amdgcn_mfma_f32_32x32x16_f16(af1, B10, acc[0], 0, 0, 0);
    acc[1] = __builtin_amdgcn_mfma_f32_32x32x16_f16(af1, B11, acc[1], 0, 0, 0);
    acc[2] = __builtin_amdgcn_mfma_f32_32x32x16_f16(af1, B12, acc[2], 0, 0, 0);
    acc[3] = __builtin_amdgcn_mfma_f32_32x32x16_f16(af1, B13, acc[3], 0, 0, 0);
    __builtin_amdgcn_s_setprio(0);
  }

  // partial denominator: combine kb halves; lanes 0..31 hold rows 0..31
  dloc += __shfl_xor(dloc, 32, 64);
  if (L < 32) Dws[(size_t)c * NROW + row] = dloc;

  // partial numerator: C/D layout col=L&31, row=(reg&3)+8*(reg>>2)+4*kb
  float* P = Pws + ((size_t)c * NROW + rb) * FDIM + (L & 31);
#pragma unroll
  for (int nt = 0; nt < 4; ++nt) {
#pragma unroll
    for (int reg = 0; reg < 16; ++reg) {
      int rr = (reg & 3) + 8 * (reg >> 2) + 4 * kb;
      P[(size_t)rr * FDIM + nt * 32] = acc[nt][reg];
    }
  }
}

// ---------------- k3: combine S partials, ELU ----------------
__global__ __launch_bounds__(256) void k3_comb(const float* __restrict__ Pws,
                                               const float* __restrict__ Dws,
                                               float* __restrict__ out, int S) {
  int g = (int)blockIdx.x * 256 + (int)threadIdx.x;  // 0..262143
  int r = g >> 5, f4 = g & 31;
  f32x4 s = {0.f, 0.f, 0.f, 0.f};
  float den = 0.f;
  for (int c2 = 0; c2 < S; ++c2) {
    s += *(const f32x4*)(Pws + ((size_t)c2 * NROW + r) * FDIM + f4 * 4);
    den += Dws[(size_t)c2 * NROW + r];
  }
  float inv = 1.0f / den;
  f32x4 o;
#pragma unroll
  for (int e = 0; e < 4; ++e) {
    float x = s[e] * inv;
    o[e] = x > 0.f ? x : expm1f(x);
  }
  *(f32x4*)(out + (size_t)r * FDIM + f4 * 4) = o;
}

extern "C" void kernel_launch(void* const* d_in, const int* in_sizes, int n_in,
                              void* d_out, int out_size, void* d_ws, size_t ws_size,
                              hipStream_t stream) {
  const float* h = (const float*)d_in[0];
  const int* adj = (const int*)d_in[1];
  const float* W = (const float*)d_in[2];
  const float* a = (const float*)d_in[3];
  float* out = (float*)d_out;
  char* ws = (char*)d_ws;
  f16* Bp = (f16*)(ws + WS_BP);
  float2* s12 = (float2*)(ws + WS_S12);
  float4* RC = (float4*)(ws + WS_RC);
  float2* EF = (float2*)(ws + WS_EF);
  float* M2v = (float*)(ws + WS_M2);

  // S chunks of j; fall back to S=2 if workspace is small (ws_size constant across calls)
  const size_t partial_bytes = (size_t)NROW * FDIM * 4;  // 4 MiB per chunk
  const size_t bm_bytes = (size_t)8 * 1024 * 1024;       // bitmap 8 MiB
  int S = (ws_size >= WS_PWS + 8 * partial_bytes + 8 * (size_t)NROW * 4 + bm_bytes) ? 8 : 2;
  float* Pws = (float*)(ws + WS_PWS);
  float* Dws = (float*)(ws + WS_PWS + (size_t)S * partial_bytes);
  unsigned* BM = (unsigned*)(ws + WS_PWS + (size_t)S * partial_bytes + (size_t)S * NROW * 4);
  int jspan = NROW / S;

  kA_wh_pack<<<dim3(2304), dim3(256), 0, stream>>>(h, W, a, adj, Bp, BM, s12, M2v);
  k1c_prep<<<dim3(32), dim3(256), 0, stream>>>(s12, M2v, RC, EF);
  k2_main<<<dim3(64 * S), dim3(256), 0, stream>>>(BM, Bp, RC, (const float*)EF, Pws, Dws, jspan);
  k3_comb<<<dim3(1024), dim3(256), 0, stream>>>(Pws, Dws, out, S);
}